// Round 9
// baseline (156.486 us; speedup 1.0000x reference)
//
#include <hip/hip_runtime.h>
#include <hip/hip_bf16.h>
#include <type_traits>

// Dims: B=8, L=2048, T=1024, Dh=1024, Dg=768, Dp=256
// Pipeline: HT=transpose(H); Q=G@Wq^T; K=H@Wk^T; S=softmax(Q@K^T/16); Z=S@HT^T
// kn_transp | kn_qproj (32x128) | kn_kproj (64x128) | kn_sgemm (256x128 sbuf) |
// kn_softmax | kn_pv (256x128, 3-buf, m201-style 2-phase interleave + counted vmcnt)
// Workspace (u16): Qbf 2M | Kbf 4M | HT 16M | S 16M = 76MB

typedef float    f32x4  __attribute__((ext_vector_type(4)));
typedef __bf16   bf16x8 __attribute__((ext_vector_type(8)));
typedef unsigned short u16x8 __attribute__((ext_vector_type(8)));

__device__ __forceinline__ unsigned short f2bf(float f) {
    union { float f; unsigned u; } x; x.f = f;
    return (unsigned short)((x.u + 0x7fffu + ((x.u >> 16) & 1u)) >> 16);
}
__device__ __forceinline__ float bf2f(unsigned short u) {
    union { unsigned u; float f; } x; x.u = ((unsigned)u) << 16;
    return x.f;
}
__device__ __forceinline__ void gload_lds16(const unsigned short* g, unsigned short* l) {
    __builtin_amdgcn_global_load_lds(
        (const __attribute__((address_space(1))) void*)g,
        (__attribute__((address_space(3))) void*)l, 16, 0, 0);
}

// ---------------- transpose: H [L,Dh] f32 -> HT [Dh,L] bf16, per batch ----------------
__global__ __launch_bounds__(256) void kn_transp(const float* __restrict__ H,
                                                 unsigned short* __restrict__ HT,
                                                 int L, int D) {
    __shared__ float tile[32][33];
    int b = blockIdx.z;
    const float* src = H + (size_t)b * L * D;
    unsigned short* dstT = HT + (size_t)b * L * D;
    int l0 = blockIdx.y * 32, d0 = blockIdx.x * 32;
    int tx = threadIdx.x, ty = threadIdx.y;
#pragma unroll
    for (int i = ty; i < 32; i += 8)
        tile[i][tx] = src[(size_t)(l0 + i) * D + d0 + tx];
    __syncthreads();
#pragma unroll
    for (int i = ty; i < 32; i += 8)
        dstT[(size_t)(d0 + i) * L + l0 + tx] = f2bf(tile[tx][i]);
}

// -------- projection: C[M,N]=A[M,K]@B^T[N,K], f32 in, bf16 out; TM x 128 tile --------
template<int TM, int WM>
__device__ __forceinline__ void proj_body(const float* __restrict__ A,
                                          const float* __restrict__ B,
                                          unsigned short* __restrict__ C,
                                          int N, int K, int gxs) {
    constexpr int WN  = 4 / WM;
    constexpr int MF  = (TM / WM) / 16;
    constexpr int NF  = (128 / WN) / 16;
    constexpr int CHA = TM * 8;
    constexpr int CHT = CHA + 1024;
    constexpr int CPT = CHT / 256;
    constexpr int BUFU = TM * 64 + 128 * 64;
    constexpr int LDSB = (2 * BUFU * 2 > TM * 132 * 4) ? 2 * BUFU * 2 : TM * 132 * 4;
    __shared__ __align__(16) char smem_raw[LDSB];
    unsigned short* base = (unsigned short*)smem_raw;
    float* st = (float*)smem_raw;

    int tid = threadIdx.x;
    int t = blockIdx.x;
    int by = t >> gxs;
    int bx = t & ((1 << gxs) - 1);
    const float* Ab = A + (size_t)by * TM * K;
    const float* Bb = B + (size_t)bx * 128 * K;

    int lane = tid & 63;
    int wid = tid >> 6;
    int wr = wid / WN, wc = wid % WN;
    int lr = lane & 15;
    int lg = lane >> 4;
    int xoff = (lane & 7) << 3;

    f32x4 rv[CPT][2];
    f32x4 acc[MF][NF] = {};

    auto LOAD = [&](int k0) {
#pragma unroll
        for (int c = 0; c < CPT; ++c) {
            int ch = c * 256 + tid;
            const float* src;
            if (ch < CHA) {
                int row = ch >> 3;
                src = Ab + (size_t)row * K + k0 + (ch & 7) * 8;
            } else {
                int bc = ch - CHA;
                int row = bc >> 3;
                src = Bb + (size_t)row * K + k0 + (bc & 7) * 8;
            }
            rv[c][0] = *(const f32x4*)src;
            rv[c][1] = *(const f32x4*)(src + 4);
        }
    };
    auto WRITE = [&](int buf) {
        unsigned short* dA = base + buf * BUFU;
        unsigned short* dB = dA + TM * 64;
#pragma unroll
        for (int c = 0; c < CPT; ++c) {
            int ch = c * 256 + tid;
            u16x8 o;
#pragma unroll
            for (int j = 0; j < 4; ++j) { o[j] = f2bf(rv[c][0][j]); o[4 + j] = f2bf(rv[c][1][j]); }
            if (ch < CHA) {
                int row = ch >> 3;
                int sl = (ch & 7) ^ (row & 7);
                *(u16x8*)&dA[row * 64 + sl * 8] = o;
            } else {
                int bc = ch - CHA;
                int row = bc >> 3;
                int sl = (bc & 7) ^ (row & 7);
                *(u16x8*)&dB[row * 64 + sl * 8] = o;
            }
        }
    };
    auto COMPUTE = [&](int buf) {
        unsigned short* pA = base + buf * BUFU;
        unsigned short* pB = pA + TM * 64;
#pragma unroll
        for (int kk = 0; kk < 2; ++kk) {
            int kb = (kk * 32 + lg * 8) ^ xoff;
            bf16x8 af[MF], bfr[NF];
#pragma unroll
            for (int m = 0; m < MF; ++m)
                af[m] = *(const bf16x8*)&pA[(wr * MF * 16 + m * 16 + lr) * 64 + kb];
#pragma unroll
            for (int n = 0; n < NF; ++n)
                bfr[n] = *(const bf16x8*)&pB[(wc * NF * 16 + n * 16 + lr) * 64 + kb];
#pragma unroll
            for (int m = 0; m < MF; ++m)
#pragma unroll
                for (int n = 0; n < NF; ++n)
                    acc[m][n] = __builtin_amdgcn_mfma_f32_16x16x32_bf16(af[m], bfr[n], acc[m][n], 0, 0, 0);
        }
    };

    int nt = K / 64;
    LOAD(0);
    WRITE(0);
    __syncthreads();
    int buf = 0;
    for (int tt = 0; tt < nt; ++tt) {
        if (tt + 1 < nt) LOAD((tt + 1) * 64);
        COMPUTE(buf);
        if (tt + 1 < nt) WRITE(buf ^ 1);
        __syncthreads();
        buf ^= 1;
    }

#pragma unroll
    for (int m = 0; m < MF; ++m) {
        int r0 = wr * MF * 16 + m * 16 + lg * 4;
#pragma unroll
        for (int n = 0; n < NF; ++n) {
            int c0 = wc * NF * 16 + n * 16 + lr;
#pragma unroll
            for (int j = 0; j < 4; ++j)
                st[(r0 + j) * 132 + c0] = acc[m][n][j];
        }
    }
    __syncthreads();
    constexpr int TPR = 256 / TM;
    constexpr int CW  = 128 / TPR;
    int r  = tid / TPR;
    int c0 = (tid % TPR) * CW;
    size_t grow = (size_t)(by * TM + r) * N + bx * 128 + c0;
#pragma unroll
    for (int g = 0; g < CW / 8; ++g) {
        f32x4 a = *(const f32x4*)&st[r * 132 + c0 + g * 8];
        f32x4 b = *(const f32x4*)&st[r * 132 + c0 + g * 8 + 4];
        u16x8 o;
#pragma unroll
        for (int j = 0; j < 4; ++j) { o[j] = f2bf(a[j]); o[4 + j] = f2bf(b[j]); }
        *(u16x8*)&C[grow + g * 8] = o;
    }
}

__global__ __launch_bounds__(256) void kn_qproj(const float* A, const float* B,
                                                unsigned short* C, int N, int K, int gxs) {
    proj_body<32, 1>(A, B, C, N, K, gxs);
}
__global__ __launch_bounds__(256) void kn_kproj(const float* A, const float* B,
                                                unsigned short* C, int N, int K, int gxs) {
    proj_body<64, 2>(A, B, C, N, K, gxs);
}

// ---------------- S-GEMM: 256x128, BK=64, 8 waves, single-buffer ----------------
__global__ __launch_bounds__(512) void kn_sgemm(const unsigned short* __restrict__ A,
                                                const unsigned short* __restrict__ B,
                                                unsigned short* __restrict__ C,
                                                int N, int K,
                                                long batchA, long batchB, long batchC,
                                                float scale, int gxs) {
    __shared__ __align__(16) char smem_raw[49152];
    unsigned short* base = (unsigned short*)smem_raw;
    float* st = (float*)smem_raw;

    int tid = threadIdx.x;
    int wg = blockIdx.x;
    int bz = wg & 7;
    int t = wg >> 3;
    int by = t >> gxs;
    int bx = t & ((1 << gxs) - 1);

    const unsigned short* Ab = A + (size_t)bz * batchA + (size_t)by * 256 * K;
    const unsigned short* Bb = B + (size_t)bz * batchB + (size_t)bx * 128 * K;
    unsigned short* Cb = C + (size_t)bz * batchC;

    int lane = tid & 63;
    int wid = tid >> 6;
    int wr = wid >> 1, wc = wid & 1;
    int lr = lane & 15;
    int lg = lane >> 4;
    int xoff = (lane & 7) << 3;

    f32x4 acc[4][4] = {};

    for (int k0 = 0; k0 < K; k0 += 64) {
#pragma unroll
        for (int c = 0; c < 6; ++c) {
            int ch = c * 512 + tid;
            if (ch < 2048) {
                int row = ch >> 3;
                int g8 = (ch & 7) ^ (row & 7);
                gload_lds16(Ab + (size_t)row * K + k0 + g8 * 8, base + ch * 8);
            } else {
                int bc = ch - 2048;
                int row = bc >> 3;
                int g8 = (bc & 7) ^ (row & 7);
                gload_lds16(Bb + (size_t)row * K + k0 + g8 * 8, base + 16384 + bc * 8);
            }
        }
        __syncthreads();
#pragma unroll
        for (int kk = 0; kk < 2; ++kk) {
            int kb = (kk * 32 + lg * 8) ^ xoff;
            bf16x8 af[4], bfr[4];
#pragma unroll
            for (int m = 0; m < 4; ++m)
                af[m] = *(const bf16x8*)&base[(wr * 64 + m * 16 + lr) * 64 + kb];
#pragma unroll
            for (int n = 0; n < 4; ++n)
                bfr[n] = *(const bf16x8*)&base[16384 + (wc * 64 + n * 16 + lr) * 64 + kb];
#pragma unroll
            for (int m = 0; m < 4; ++m)
#pragma unroll
                for (int n = 0; n < 4; ++n)
                    acc[m][n] = __builtin_amdgcn_mfma_f32_16x16x32_bf16(af[m], bfr[n], acc[m][n], 0, 0, 0);
        }
        __syncthreads();
    }

#pragma unroll
    for (int q = 0; q < 4; ++q) {
        if (wr == q) {
#pragma unroll
            for (int m = 0; m < 4; ++m) {
                int rl = m * 16 + lg * 4;
#pragma unroll
                for (int n = 0; n < 4; ++n) {
                    int col = wc * 64 + n * 16 + lr;
#pragma unroll
                    for (int j = 0; j < 4; ++j)
                        st[(rl + j) * 132 + col] = acc[m][n][j] * scale;
                }
            }
        }
        __syncthreads();
        int r = tid >> 3;
        int c0 = (tid & 7) * 16;
        size_t grow = (size_t)(by * 256 + q * 64 + r) * N + bx * 128 + c0;
#pragma unroll
        for (int g = 0; g < 2; ++g) {
            f32x4 a = *(const f32x4*)&st[r * 132 + c0 + g * 8];
            f32x4 b = *(const f32x4*)&st[r * 132 + c0 + g * 8 + 4];
            u16x8 o;
#pragma unroll
            for (int j = 0; j < 4; ++j) { o[j] = f2bf(a[j]); o[4 + j] = f2bf(b[j]); }
            *(u16x8*)&Cb[grow + g * 8] = o;
        }
        __syncthreads();
    }
}

// ------- PV: 256x128, BK=64, 8 waves, 3-buf, m201-style 2-phase interleave -------
// Per K-tile: 2 phases; each phase = {8 swizzled ds_read_b128 + issue 3 gload_lds of
// tile t+2} -> s_barrier -> lgkmcnt(0) -> 16 MFMA (setprio-wrapped) -> [kk==1:
// vmcnt(6), never 0 in steady state] -> s_barrier.
__global__ __launch_bounds__(512) void kn_pv(const unsigned short* __restrict__ A,
                                             const unsigned short* __restrict__ B,
                                             float* __restrict__ C,
                                             int N, int K,
                                             long batchA, long batchB, long batchC,
                                             int gxs) {
    __shared__ __align__(16) char smem_raw[3 * 49152];       // 144KB: 3 bufs of A32+B16
    unsigned short* base = (unsigned short*)smem_raw;
    float* st = (float*)smem_raw;

    int tid = threadIdx.x;
    int wg = blockIdx.x;
    int bz = wg & 7;
    int t = wg >> 3;
    int by = t >> gxs;
    int bx = t & ((1 << gxs) - 1);

    const unsigned short* Ab = A + (size_t)bz * batchA + (size_t)by * 256 * K;
    const unsigned short* Bb = B + (size_t)bz * batchB + (size_t)bx * 128 * K;
    float* Cb = C + (size_t)bz * batchC;

    int lane = tid & 63;
    int wid = tid >> 6;
    int wr = wid >> 1, wc = wid & 1;
    int lr = lane & 15;
    int lg = lane >> 4;
    int xoff = (lane & 7) << 3;

    f32x4 acc[4][4] = {};

    // stage chunks [half*1536, half*1536+1536) of the 3072-chunk tile
    auto STAGE_HALF = [&](int buf, int k0, int half) {
        unsigned short* dA = base + buf * 24576;
        unsigned short* dB = dA + 16384;
#pragma unroll
        for (int c = 0; c < 3; ++c) {
            int ch = half * 1536 + c * 512 + tid;
            if (ch < 2048) {
                int row = ch >> 3;
                int g8 = (ch & 7) ^ (row & 7);
                gload_lds16(Ab + (size_t)row * K + k0 + g8 * 8, dA + ch * 8);
            } else {
                int bc = ch - 2048;
                int row = bc >> 3;
                int g8 = (bc & 7) ^ (row & 7);
                gload_lds16(Bb + (size_t)row * K + k0 + g8 * 8, dB + bc * 8);
            }
        }
    };

    int nt = K / 64;                           // 32
    STAGE_HALF(0, 0, 0);   STAGE_HALF(0, 0, 1);
    STAGE_HALF(1, 64, 0);  STAGE_HALF(1, 64, 1);
    asm volatile("s_waitcnt vmcnt(6)" ::: "memory");   // tile0 landed
    __builtin_amdgcn_s_barrier();
    __builtin_amdgcn_sched_barrier(0);

    int cur = 0;
    for (int tt = 0; tt < nt; ++tt) {
        int nb = (cur >= 1) ? cur - 1 : cur + 2;          // (cur+2)%3
        unsigned short* pA = base + cur * 24576;
        unsigned short* pB = pA + 16384;
#pragma unroll
        for (int kk = 0; kk < 2; ++kk) {
            // phase: ds_read frags for this kk
            int kb = (kk * 32 + lg * 8) ^ xoff;
            bf16x8 af[4], bfr[4];
#pragma unroll
            for (int m = 0; m < 4; ++m)
                af[m] = *(const bf16x8*)&pA[(wr * 64 + m * 16 + lr) * 64 + kb];
#pragma unroll
            for (int n = 0; n < 4; ++n)
                bfr[n] = *(const bf16x8*)&pB[(wc * 64 + n * 16 + lr) * 64 + kb];
            // issue half the next-next tile's staging
            if (tt + 2 < nt) STAGE_HALF(nb, (tt + 2) * 64, kk);
            __builtin_amdgcn_sched_barrier(0);
            __builtin_amdgcn_s_barrier();
            asm volatile("s_waitcnt lgkmcnt(0)" ::: "memory");
            __builtin_amdgcn_sched_barrier(0);
            __builtin_amdgcn_s_setprio(1);
#pragma unroll
            for (int m = 0; m < 4; ++m)
#pragma unroll
                for (int n = 0; n < 4; ++n)
                    acc[m][n] = __builtin_amdgcn_mfma_f32_16x16x32_bf16(af[m], bfr[n], acc[m][n], 0, 0, 0);
            __builtin_amdgcn_s_setprio(0);
            if (kk == 1) {                      // tile boundary: counted wait
                if (tt + 2 < nt)      asm volatile("s_waitcnt vmcnt(6)" ::: "memory");
                else if (tt + 1 < nt) asm volatile("s_waitcnt vmcnt(0)" ::: "memory");
            }
            __builtin_amdgcn_sched_barrier(0);
            __builtin_amdgcn_s_barrier();
        }
        cur = (cur == 2) ? 0 : cur + 1;
    }
    asm volatile("s_waitcnt vmcnt(0)" ::: "memory");
    __builtin_amdgcn_s_barrier();              // LDS quiet before epilogue reuse

    // epilogue: 4 quarters via st[64][132]
#pragma unroll
    for (int q = 0; q < 4; ++q) {
        if (wr == q) {
#pragma unroll
            for (int m = 0; m < 4; ++m) {
                int rl = m * 16 + lg * 4;
#pragma unroll
                for (int n = 0; n < 4; ++n) {
                    int col = wc * 64 + n * 16 + lr;
#pragma unroll
                    for (int j = 0; j < 4; ++j)
                        st[(rl + j) * 132 + col] = acc[m][n][j];
                }
            }
        }
        __syncthreads();
        int r = tid >> 3;
        int c0 = (tid & 7) * 16;
        size_t grow = (size_t)(by * 256 + q * 64 + r) * N + bx * 128 + c0;
#pragma unroll
        for (int g = 0; g < 4; ++g) {
            f32x4 v = *(const f32x4*)&st[r * 132 + c0 + g * 4];
            *(f32x4*)&Cb[grow + g * 4] = v;
        }
        __syncthreads();
    }
}

// ---------------- row softmax in place on bf16 [rows, L=2048] ----------------
__global__ __launch_bounds__(256) void kn_softmax(unsigned short* __restrict__ S, int L) {
    __shared__ float red[8];
    size_t row = blockIdx.x;
    unsigned short* p = S + row * (size_t)L;
    int tid = threadIdx.x;
    int lane = tid & 63;
    int wid = tid >> 6;

    u16x8 u = *(const u16x8*)(p + tid * 8);
    float v[8];
#pragma unroll
    for (int j = 0; j < 8; ++j) v[j] = bf2f(u[j]);

    float mx = v[0];
#pragma unroll
    for (int j = 1; j < 8; ++j) mx = fmaxf(mx, v[j]);
#pragma unroll
    for (int off = 32; off > 0; off >>= 1) mx = fmaxf(mx, __shfl_xor(mx, off));
    if (lane == 0) red[wid] = mx;
    __syncthreads();
    mx = fmaxf(fmaxf(red[0], red[1]), fmaxf(red[2], red[3]));

    float s = 0.f;
#pragma unroll
    for (int j = 0; j < 8; ++j) { v[j] = __expf(v[j] - mx); s += v[j]; }
#pragma unroll
    for (int off = 32; off > 0; off >>= 1) s += __shfl_xor(s, off);
    if (lane == 0) red[4 + wid] = s;
    __syncthreads();
    s = red[4] + red[5] + red[6] + red[7];
    float inv = 1.0f / s;

    u16x8 o;
#pragma unroll
    for (int j = 0; j < 8; ++j) o[j] = f2bf(v[j] * inv);
    *(u16x8*)(p + tid * 8) = o;
}

extern "C" void kernel_launch(void* const* d_in, const int* in_sizes, int n_in,
                              void* d_out, int out_size, void* d_ws, size_t ws_size,
                              hipStream_t stream) {
    constexpr int B = 8, L = 2048, T = 1024, Dh = 1024, Dg = 768, Dp = 256;
    const float* H  = (const float*)d_in[0];
    const float* G  = (const float*)d_in[1];
    const float* Wq = (const float*)d_in[2];
    const float* Wk = (const float*)d_in[3];
    float* Z = (float*)d_out;

    unsigned short* Qbf = (unsigned short*)d_ws;             // B*T*Dp  = 2M
    unsigned short* Kbf = Qbf + (size_t)B * T * Dp;          // B*L*Dp  = 4M
    unsigned short* HT  = Kbf + (size_t)B * L * Dp;          // B*Dh*L  = 16M
    unsigned short* S   = HT  + (size_t)B * Dh * L;          // B*T*L   = 16M

    kn_transp<<<dim3(Dh / 32, L / 32, B), dim3(32, 8), 0, stream>>>(H, HT, L, Dh);

    kn_qproj<<<(B * T / 32) * (Dp / 128), 256, 0, stream>>>(G, Wq, Qbf, Dp, Dg, 1);

    kn_kproj<<<(B * L / 64) * (Dp / 128), 256, 0, stream>>>(H, Wk, Kbf, Dp, Dh, 1);

    kn_sgemm<<<(T / 256) * (L / 128) * B, 512, 0, stream>>>
        (Qbf, Kbf, S, L, Dp, (long)T * Dp, (long)L * Dp, (long)T * L, 0.0625f, 4);

    kn_softmax<<<dim3(B * T), 256, 0, stream>>>(S, L);

    kn_pv<<<(T / 256) * (Dh / 128) * B, 512, 0, stream>>>
        (S, HT, Z, Dh, L, (long)T * L, (long)Dh * L, (long)T * Dh, 3);
}

// Round 10
// 147.515 us; speedup vs baseline: 1.0608x; 1.0608x over previous
//
#include <hip/hip_runtime.h>
#include <hip/hip_bf16.h>
#include <type_traits>

// Dims: B=8, L=2048, T=1024, Dh=1024, Dg=768, Dp=256
// Pipeline: HT=transpose(H); Q=G@Wq^T; K=H@Wk^T; Sexp=exp(Q@K^T/16) [+rowsum atomics];
//           Z = (Sexp @ HT^T) / rowsum   -- softmax fused into sgemm/pv epilogues.
// kn_transp | kn_qproj (32x128) | kn_kproj (64x128) | kn_sgemm (256x128 + exp/rowsum) |
// kn_pv (256x128, 3-buf, register-double-buffered frags, 1 barrier/tile)
// Workspace (u16): Qbf 2M | Kbf 4M | HT 16M | S 16M | rowsum f32 B*T

typedef float    f32x4  __attribute__((ext_vector_type(4)));
typedef __bf16   bf16x8 __attribute__((ext_vector_type(8)));
typedef unsigned short u16x8 __attribute__((ext_vector_type(8)));

__device__ __forceinline__ unsigned short f2bf(float f) {
    union { float f; unsigned u; } x; x.f = f;
    return (unsigned short)((x.u + 0x7fffu + ((x.u >> 16) & 1u)) >> 16);
}
__device__ __forceinline__ float bf2f(unsigned short u) {
    union { unsigned u; float f; } x; x.u = ((unsigned)u) << 16;
    return x.f;
}
__device__ __forceinline__ void gload_lds16(const unsigned short* g, unsigned short* l) {
    __builtin_amdgcn_global_load_lds(
        (const __attribute__((address_space(1))) void*)g,
        (__attribute__((address_space(3))) void*)l, 16, 0, 0);
}

// ---------------- transpose: H [L,Dh] f32 -> HT [Dh,L] bf16, per batch ----------------
__global__ __launch_bounds__(256) void kn_transp(const float* __restrict__ H,
                                                 unsigned short* __restrict__ HT,
                                                 int L, int D) {
    __shared__ float tile[32][33];
    int b = blockIdx.z;
    const float* src = H + (size_t)b * L * D;
    unsigned short* dstT = HT + (size_t)b * L * D;
    int l0 = blockIdx.y * 32, d0 = blockIdx.x * 32;
    int tx = threadIdx.x, ty = threadIdx.y;
#pragma unroll
    for (int i = ty; i < 32; i += 8)
        tile[i][tx] = src[(size_t)(l0 + i) * D + d0 + tx];
    __syncthreads();
#pragma unroll
    for (int i = ty; i < 32; i += 8)
        dstT[(size_t)(d0 + i) * L + l0 + tx] = f2bf(tile[tx][i]);
}

// -------- projection: C[M,N]=A[M,K]@B^T[N,K], f32 in, bf16 out; TM x 128 tile --------
template<int TM, int WM>
__device__ __forceinline__ void proj_body(const float* __restrict__ A,
                                          const float* __restrict__ B,
                                          unsigned short* __restrict__ C,
                                          int N, int K, int gxs) {
    constexpr int WN  = 4 / WM;
    constexpr int MF  = (TM / WM) / 16;
    constexpr int NF  = (128 / WN) / 16;
    constexpr int CHA = TM * 8;
    constexpr int CHT = CHA + 1024;
    constexpr int CPT = CHT / 256;
    constexpr int BUFU = TM * 64 + 128 * 64;
    constexpr int LDSB = (2 * BUFU * 2 > TM * 132 * 4) ? 2 * BUFU * 2 : TM * 132 * 4;
    __shared__ __align__(16) char smem_raw[LDSB];
    unsigned short* base = (unsigned short*)smem_raw;
    float* st = (float*)smem_raw;

    int tid = threadIdx.x;
    int t = blockIdx.x;
    int by = t >> gxs;
    int bx = t & ((1 << gxs) - 1);
    const float* Ab = A + (size_t)by * TM * K;
    const float* Bb = B + (size_t)bx * 128 * K;

    int lane = tid & 63;
    int wid = tid >> 6;
    int wr = wid / WN, wc = wid % WN;
    int lr = lane & 15;
    int lg = lane >> 4;
    int xoff = (lane & 7) << 3;

    f32x4 rv[CPT][2];
    f32x4 acc[MF][NF] = {};

    auto LOAD = [&](int k0) {
#pragma unroll
        for (int c = 0; c < CPT; ++c) {
            int ch = c * 256 + tid;
            const float* src;
            if (ch < CHA) {
                int row = ch >> 3;
                src = Ab + (size_t)row * K + k0 + (ch & 7) * 8;
            } else {
                int bc = ch - CHA;
                int row = bc >> 3;
                src = Bb + (size_t)row * K + k0 + (bc & 7) * 8;
            }
            rv[c][0] = *(const f32x4*)src;
            rv[c][1] = *(const f32x4*)(src + 4);
        }
    };
    auto WRITE = [&](int buf) {
        unsigned short* dA = base + buf * BUFU;
        unsigned short* dB = dA + TM * 64;
#pragma unroll
        for (int c = 0; c < CPT; ++c) {
            int ch = c * 256 + tid;
            u16x8 o;
#pragma unroll
            for (int j = 0; j < 4; ++j) { o[j] = f2bf(rv[c][0][j]); o[4 + j] = f2bf(rv[c][1][j]); }
            if (ch < CHA) {
                int row = ch >> 3;
                int sl = (ch & 7) ^ (row & 7);
                *(u16x8*)&dA[row * 64 + sl * 8] = o;
            } else {
                int bc = ch - CHA;
                int row = bc >> 3;
                int sl = (bc & 7) ^ (row & 7);
                *(u16x8*)&dB[row * 64 + sl * 8] = o;
            }
        }
    };
    auto COMPUTE = [&](int buf) {
        unsigned short* pA = base + buf * BUFU;
        unsigned short* pB = pA + TM * 64;
#pragma unroll
        for (int kk = 0; kk < 2; ++kk) {
            int kb = (kk * 32 + lg * 8) ^ xoff;
            bf16x8 af[MF], bfr[NF];
#pragma unroll
            for (int m = 0; m < MF; ++m)
                af[m] = *(const bf16x8*)&pA[(wr * MF * 16 + m * 16 + lr) * 64 + kb];
#pragma unroll
            for (int n = 0; n < NF; ++n)
                bfr[n] = *(const bf16x8*)&pB[(wc * NF * 16 + n * 16 + lr) * 64 + kb];
#pragma unroll
            for (int m = 0; m < MF; ++m)
#pragma unroll
                for (int n = 0; n < NF; ++n)
                    acc[m][n] = __builtin_amdgcn_mfma_f32_16x16x32_bf16(af[m], bfr[n], acc[m][n], 0, 0, 0);
        }
    };

    int nt = K / 64;
    LOAD(0);
    WRITE(0);
    __syncthreads();
    int buf = 0;
    for (int tt = 0; tt < nt; ++tt) {
        if (tt + 1 < nt) LOAD((tt + 1) * 64);
        COMPUTE(buf);
        if (tt + 1 < nt) WRITE(buf ^ 1);
        __syncthreads();
        buf ^= 1;
    }

#pragma unroll
    for (int m = 0; m < MF; ++m) {
        int r0 = wr * MF * 16 + m * 16 + lg * 4;
#pragma unroll
        for (int n = 0; n < NF; ++n) {
            int c0 = wc * NF * 16 + n * 16 + lr;
#pragma unroll
            for (int j = 0; j < 4; ++j)
                st[(r0 + j) * 132 + c0] = acc[m][n][j];
        }
    }
    __syncthreads();
    constexpr int TPR = 256 / TM;
    constexpr int CW  = 128 / TPR;
    int r  = tid / TPR;
    int c0 = (tid % TPR) * CW;
    size_t grow = (size_t)(by * TM + r) * N + bx * 128 + c0;
#pragma unroll
    for (int g = 0; g < CW / 8; ++g) {
        f32x4 a = *(const f32x4*)&st[r * 132 + c0 + g * 8];
        f32x4 b = *(const f32x4*)&st[r * 132 + c0 + g * 8 + 4];
        u16x8 o;
#pragma unroll
        for (int j = 0; j < 4; ++j) { o[j] = f2bf(a[j]); o[4 + j] = f2bf(b[j]); }
        *(u16x8*)&C[grow + g * 8] = o;
    }
}

__global__ __launch_bounds__(256) void kn_qproj(const float* A, const float* B,
                                                unsigned short* C, int N, int K, int gxs) {
    proj_body<32, 1>(A, B, C, N, K, gxs);
}
__global__ __launch_bounds__(256) void kn_kproj(const float* A, const float* B,
                                                unsigned short* C, int N, int K, int gxs) {
    proj_body<64, 2>(A, B, C, N, K, gxs);
}

// ------- S-GEMM: 256x128, BK=64, 8 waves, single-buffer; epilogue stores exp(s) and
//         atomically accumulates f32 row sums (softmax denominator). -------
__global__ __launch_bounds__(512) void kn_sgemm(const unsigned short* __restrict__ A,
                                                const unsigned short* __restrict__ B,
                                                unsigned short* __restrict__ C,
                                                float* __restrict__ rowsum,
                                                int N, int K, int Trows,
                                                long batchA, long batchB, long batchC,
                                                float scale, int gxs) {
    __shared__ __align__(16) char smem_raw[49152];
    unsigned short* base = (unsigned short*)smem_raw;
    float* st = (float*)smem_raw;

    int tid = threadIdx.x;
    int wg = blockIdx.x;
    int bz = wg & 7;
    int t = wg >> 3;
    int by = t >> gxs;
    int bx = t & ((1 << gxs) - 1);

    const unsigned short* Ab = A + (size_t)bz * batchA + (size_t)by * 256 * K;
    const unsigned short* Bb = B + (size_t)bz * batchB + (size_t)bx * 128 * K;
    unsigned short* Cb = C + (size_t)bz * batchC;
    float* rs = rowsum + (size_t)bz * Trows;

    int lane = tid & 63;
    int wid = tid >> 6;
    int wr = wid >> 1, wc = wid & 1;
    int lr = lane & 15;
    int lg = lane >> 4;
    int xoff = (lane & 7) << 3;

    f32x4 acc[4][4] = {};

    for (int k0 = 0; k0 < K; k0 += 64) {
#pragma unroll
        for (int c = 0; c < 6; ++c) {
            int ch = c * 512 + tid;
            if (ch < 2048) {
                int row = ch >> 3;
                int g8 = (ch & 7) ^ (row & 7);
                gload_lds16(Ab + (size_t)row * K + k0 + g8 * 8, base + ch * 8);
            } else {
                int bc = ch - 2048;
                int row = bc >> 3;
                int g8 = (bc & 7) ^ (row & 7);
                gload_lds16(Bb + (size_t)row * K + k0 + g8 * 8, base + 16384 + bc * 8);
            }
        }
        __syncthreads();
#pragma unroll
        for (int kk = 0; kk < 2; ++kk) {
            int kb = (kk * 32 + lg * 8) ^ xoff;
            bf16x8 af[4], bfr[4];
#pragma unroll
            for (int m = 0; m < 4; ++m)
                af[m] = *(const bf16x8*)&base[(wr * 64 + m * 16 + lr) * 64 + kb];
#pragma unroll
            for (int n = 0; n < 4; ++n)
                bfr[n] = *(const bf16x8*)&base[16384 + (wc * 64 + n * 16 + lr) * 64 + kb];
#pragma unroll
            for (int m = 0; m < 4; ++m)
#pragma unroll
                for (int n = 0; n < 4; ++n)
                    acc[m][n] = __builtin_amdgcn_mfma_f32_16x16x32_bf16(af[m], bfr[n], acc[m][n], 0, 0, 0);
        }
        __syncthreads();
    }

#pragma unroll
    for (int q = 0; q < 4; ++q) {
        if (wr == q) {
#pragma unroll
            for (int m = 0; m < 4; ++m) {
                int rl = m * 16 + lg * 4;
#pragma unroll
                for (int n = 0; n < 4; ++n) {
                    int col = wc * 64 + n * 16 + lr;
#pragma unroll
                    for (int j = 0; j < 4; ++j)
                        st[(rl + j) * 132 + col] = acc[m][n][j] * scale;
                }
            }
        }
        __syncthreads();
        int r = tid >> 3;
        int c0 = (tid & 7) * 16;
        size_t grow = (size_t)(by * 256 + q * 64 + r) * N + bx * 128 + c0;
        float psum = 0.f;
#pragma unroll
        for (int g = 0; g < 2; ++g) {
            f32x4 a = *(const f32x4*)&st[r * 132 + c0 + g * 8];
            f32x4 b = *(const f32x4*)&st[r * 132 + c0 + g * 8 + 4];
            u16x8 o;
#pragma unroll
            for (int j = 0; j < 4; ++j) {
                float pa = __expf(a[j]);
                float pb = __expf(b[j]);
                o[j] = f2bf(pa); o[4 + j] = f2bf(pb);
                // sum the bf16-rounded values so denominator matches PV's numerator
                psum += bf2f(o[j]) + bf2f(o[4 + j]);
            }
            *(u16x8*)&Cb[grow + g * 8] = o;
        }
        psum += __shfl_xor(psum, 1);
        psum += __shfl_xor(psum, 2);
        psum += __shfl_xor(psum, 4);
        if ((tid & 7) == 0)
            atomicAdd(&rs[by * 256 + q * 64 + r], psum);
        __syncthreads();
    }
}

// ------- PV: 256x128, BK=64, 8 waves, 3-buf LDS, register-dbuf frags, 1 barrier/tile.
//         Epilogue divides by rowsum (softmax denominator). -------
__global__ __launch_bounds__(512) void kn_pv(const unsigned short* __restrict__ A,
                                             const unsigned short* __restrict__ B,
                                             float* __restrict__ C,
                                             const float* __restrict__ rowsum,
                                             int N, int K, int Trows,
                                             long batchA, long batchB, long batchC,
                                             int gxs) {
    __shared__ __align__(16) char smem_raw[3 * 49152];       // 144KB
    unsigned short* base = (unsigned short*)smem_raw;
    float* st = (float*)smem_raw;

    int tid = threadIdx.x;
    int wg = blockIdx.x;
    int bz = wg & 7;
    int t = wg >> 3;
    int by = t >> gxs;
    int bx = t & ((1 << gxs) - 1);

    const unsigned short* Ab = A + (size_t)bz * batchA + (size_t)by * 256 * K;
    const unsigned short* Bb = B + (size_t)bz * batchB + (size_t)bx * 128 * K;
    float* Cb = C + (size_t)bz * batchC;
    const float* rs = rowsum + (size_t)bz * Trows;

    int lane = tid & 63;
    int wid = tid >> 6;
    int wr = wid >> 1, wc = wid & 1;
    int lr = lane & 15;
    int lg = lane >> 4;
    int xoff = (lane & 7) << 3;

    f32x4 acc[4][4] = {};
    bf16x8 fA0[4], fB0[4], fA1[4], fB1[4];

    auto STAGE_HALF = [&](int buf, int k0, int half) {
        unsigned short* dA = base + buf * 24576;
        unsigned short* dB = dA + 16384;
#pragma unroll
        for (int c = 0; c < 3; ++c) {
            int ch = half * 1536 + c * 512 + tid;
            if (ch < 2048) {
                int row = ch >> 3;
                int g8 = (ch & 7) ^ (row & 7);
                gload_lds16(Ab + (size_t)row * K + k0 + g8 * 8, dA + ch * 8);
            } else {
                int bc = ch - 2048;
                int row = bc >> 3;
                int g8 = (bc & 7) ^ (row & 7);
                gload_lds16(Bb + (size_t)row * K + k0 + g8 * 8, dB + bc * 8);
            }
        }
    };
    auto LDFRAG = [&](int buf, int kk, bf16x8* fa, bf16x8* fb) {
        unsigned short* pA = base + buf * 24576;
        unsigned short* pB = pA + 16384;
        int kb = (kk * 32 + lg * 8) ^ xoff;
#pragma unroll
        for (int m = 0; m < 4; ++m)
            fa[m] = *(const bf16x8*)&pA[(wr * 64 + m * 16 + lr) * 64 + kb];
#pragma unroll
        for (int n = 0; n < 4; ++n)
            fb[n] = *(const bf16x8*)&pB[(wc * 64 + n * 16 + lr) * 64 + kb];
    };

    int nt = K / 64;                           // 32
    STAGE_HALF(0, 0, 0);   STAGE_HALF(0, 0, 1);
    STAGE_HALF(1, 64, 0);  STAGE_HALF(1, 64, 1);
    asm volatile("s_waitcnt vmcnt(6)" ::: "memory");   // tile0 landed
    __builtin_amdgcn_s_barrier();
    LDFRAG(0, 0, fA0, fB0);

    int cur = 0;
    for (int tt = 0; tt < nt; ++tt) {
        int nb  = (cur >= 1) ? cur - 1 : 2;    // (cur+2)%3: buffer to restage
        int nxt = (cur == 2) ? 0 : cur + 1;
        // phase 0: issue next-frag reads + staging, then MFMA current frags
        if (tt + 2 < nt) STAGE_HALF(nb, (tt + 2) * 64, 0);
        LDFRAG(cur, 1, fA1, fB1);
        __builtin_amdgcn_sched_barrier(0);
        __builtin_amdgcn_s_setprio(1);
#pragma unroll
        for (int m = 0; m < 4; ++m)
#pragma unroll
            for (int n = 0; n < 4; ++n)
                acc[m][n] = __builtin_amdgcn_mfma_f32_16x16x32_bf16(fA0[m], fB0[n], acc[m][n], 0, 0, 0);
        __builtin_amdgcn_s_setprio(0);
        __builtin_amdgcn_sched_barrier(0);
        // phase 1
        if (tt + 2 < nt) STAGE_HALF(nb, (tt + 2) * 64, 1);
        __builtin_amdgcn_sched_barrier(0);
        __builtin_amdgcn_s_setprio(1);
#pragma unroll
        for (int m = 0; m < 4; ++m)
#pragma unroll
            for (int n = 0; n < 4; ++n)
                acc[m][n] = __builtin_amdgcn_mfma_f32_16x16x32_bf16(fA1[m], fB1[n], acc[m][n], 0, 0, 0);
        __builtin_amdgcn_s_setprio(0);
        __builtin_amdgcn_sched_barrier(0);
        // tile boundary: counted wait, prefetch next tile's kk=0 frags, one barrier
        if (tt + 1 < nt) {
            if (tt + 2 < nt) asm volatile("s_waitcnt vmcnt(6)" ::: "memory");
            else             asm volatile("s_waitcnt vmcnt(0)" ::: "memory");
            LDFRAG(nxt, 0, fA0, fB0);
            __builtin_amdgcn_sched_barrier(0);
            __builtin_amdgcn_s_barrier();
        }
        cur = nxt;
    }
    __syncthreads();                            // all LDS reads done before st reuse

    // epilogue: 4 quarters via st[64][132], divide by rowsum
#pragma unroll
    for (int q = 0; q < 4; ++q) {
        if (wr == q) {
#pragma unroll
            for (int m = 0; m < 4; ++m) {
                int rl = m * 16 + lg * 4;
#pragma unroll
                for (int n = 0; n < 4; ++n) {
                    int col = wc * 64 + n * 16 + lr;
#pragma unroll
                    for (int j = 0; j < 4; ++j)
                        st[(rl + j) * 132 + col] = acc[m][n][j];
                }
            }
        }
        __syncthreads();
        int r = tid >> 3;
        int c0 = (tid & 7) * 16;
        float inv = 1.0f / rs[by * 256 + q * 64 + r];
        size_t grow = (size_t)(by * 256 + q * 64 + r) * N + bx * 128 + c0;
#pragma unroll
        for (int g = 0; g < 4; ++g) {
            f32x4 v = *(const f32x4*)&st[r * 132 + c0 + g * 4];
#pragma unroll
            for (int j = 0; j < 4; ++j) v[j] *= inv;
            *(f32x4*)&Cb[grow + g * 4] = v;
        }
        __syncthreads();
    }
}

extern "C" void kernel_launch(void* const* d_in, const int* in_sizes, int n_in,
                              void* d_out, int out_size, void* d_ws, size_t ws_size,
                              hipStream_t stream) {
    constexpr int B = 8, L = 2048, T = 1024, Dh = 1024, Dg = 768, Dp = 256;
    const float* H  = (const float*)d_in[0];
    const float* G  = (const float*)d_in[1];
    const float* Wq = (const float*)d_in[2];
    const float* Wk = (const float*)d_in[3];
    float* Z = (float*)d_out;

    unsigned short* Qbf = (unsigned short*)d_ws;             // B*T*Dp  = 2M
    unsigned short* Kbf = Qbf + (size_t)B * T * Dp;          // B*L*Dp  = 4M
    unsigned short* HT  = Kbf + (size_t)B * L * Dp;          // B*Dh*L  = 16M
    unsigned short* S   = HT  + (size_t)B * Dh * L;          // B*T*L   = 16M
    float* rowsum = (float*)(S + (size_t)B * T * L);         // B*T f32

    hipMemsetAsync(rowsum, 0, (size_t)B * T * sizeof(float), stream);

    kn_transp<<<dim3(Dh / 32, L / 32, B), dim3(32, 8), 0, stream>>>(H, HT, L, Dh);

    kn_qproj<<<(B * T / 32) * (Dp / 128), 256, 0, stream>>>(G, Wq, Qbf, Dp, Dg, 1);

    kn_kproj<<<(B * L / 64) * (Dp / 128), 256, 0, stream>>>(H, Wk, Kbf, Dp, Dh, 1);

    kn_sgemm<<<(T / 256) * (L / 128) * B, 512, 0, stream>>>
        (Qbf, Kbf, S, rowsum, L, Dp, T, (long)T * Dp, (long)L * Dp, (long)T * L, 0.0625f, 4);

    kn_pv<<<(T / 256) * (Dh / 128) * B, 512, 0, stream>>>
        (S, HT, Z, rowsum, Dh, L, T, (long)T * L, (long)Dh * L, (long)T * Dh, 3);
}